// Round 8
// baseline (468.737 us; speedup 1.0000x reference)
//
#include <hip/hip_runtime.h>
#include <math.h>

// Problem constants (reference: N=8192, DIM=512, TOPK=10, all fp32)
#define NROWS 8192
#define DIMK  512
#define TOPK  10
#define SCALE 0.044194173824159223f   // fp32(512**-0.5)

// Phase-1 embed GEMM tiling (fp32 VALU): 128x64 tile, 8x4 micro-tile.
#define ETM 128
#define ETN 64
#define ETK 32
#define NTHREADS 256

// Screen GEMM tiling (bf16 MFMA) — strip structure (round-5/7, measured)
#define BM 128
#define BN 128
#define BK 32
#define NS2 16                    // column strips
#define SCOLS2 (NROWS / NS2)      // 512 cols per strip (4 tiles)
#define NQ 256                    // 32-col groups per row (8192/32)
#define CAP 64                    // max candidates per row
#define TMARGIN 2.0f              // >> 3-sigma of (bf16-gemm + bf16-storage) noise

typedef __attribute__((ext_vector_type(8))) short bf16x8;   // 8 bf16 = 4 VGPRs
typedef __attribute__((ext_vector_type(4))) float f32x4;

__device__ __forceinline__ unsigned short f2bf(float f) {   // RNE fp32->bf16
  unsigned int u = __float_as_uint(f);
  u = (u + 0x7FFF + ((u >> 16) & 1)) >> 16;
  return (unsigned short)u;
}

// async global->LDS, 16B per lane; lds ptr must be wave-uniform base
__device__ __forceinline__ void gld16(const void* g, const void* lds) {
  __builtin_amdgcn_global_load_lds(
      (const __attribute__((address_space(1))) void*)g,
      (__attribute__((address_space(3))) void*)lds, 16, 0, 0);
}

// ---------------------------------------------------------------------------
// Phase 1: E = X @ W^T + b (fp32 exact) + bf16 copies. 128x64 tile, 8x4
// micro-tile. Per-element k-chain: sequential ascending fmaf + bias at end
// -> BIT-IDENTICAL Eh/Et vs rounds 3-7 (rank near-ties depend on it).
// ---------------------------------------------------------------------------
__global__ __launch_bounds__(NTHREADS, 4)
void embed_gemm(const float* __restrict__ X,
                const float* __restrict__ Wh, const float* __restrict__ bh,
                const float* __restrict__ Wt, const float* __restrict__ bt,
                float* __restrict__ Eh, float* __restrict__ Et,
                unsigned short* __restrict__ Ehb, unsigned short* __restrict__ Etb) {
  __shared__ float As[ETK][ETM + 4];   // d-major, 16.5 KB
  __shared__ float Bs[ETK][ETN + 4];   // 8.5 KB

  const int tid = threadIdx.x;
  const int rowBase = blockIdx.x * ETM;
  const int colBase = blockIdx.y * ETN;          // 0..960 over [Wh|Wt]
  const float* W  = (colBase < DIMK) ? Wh : Wt;
  const float* bb = (colBase < DIMK) ? bh : bt;
  float* Out            = (colBase < DIMK) ? Eh : Et;
  unsigned short* Outb  = (colBase < DIMK) ? Ehb : Etb;
  const int colOff = colBase & (DIMK - 1);

  const int tx = tid & 15, ty = tid >> 4;
  float acc[8][4];
#pragma unroll
  for (int r = 0; r < 8; ++r)
#pragma unroll
    for (int c = 0; c < 4; ++c) acc[r][c] = 0.f;

  for (int kt = 0; kt < DIMK; kt += ETK) {
    __syncthreads();
#pragma unroll
    for (int u = 0; u < 4; ++u) {      // A tile: 1024 float4
      const int idx = tid + u * NTHREADS;
      const int r = idx >> 3;
      const int dc = idx & 7;
      const float4 av = *(const float4*)&X[(size_t)(rowBase + r) * DIMK + kt + dc * 4];
      As[dc * 4 + 0][r] = av.x; As[dc * 4 + 1][r] = av.y;
      As[dc * 4 + 2][r] = av.z; As[dc * 4 + 3][r] = av.w;
    }
#pragma unroll
    for (int u = 0; u < 2; ++u) {      // B tile: 512 float4
      const int idx = tid + u * NTHREADS;
      const int r = idx >> 3;
      const int dc = idx & 7;
      const float4 bv = *(const float4*)&W[(size_t)(colOff + r) * DIMK + kt + dc * 4];
      Bs[dc * 4 + 0][r] = bv.x; Bs[dc * 4 + 1][r] = bv.y;
      Bs[dc * 4 + 2][r] = bv.z; Bs[dc * 4 + 3][r] = bv.w;
    }
    __syncthreads();
#pragma unroll 8
    for (int k = 0; k < ETK; ++k) {
      const float4 a0 = *(const float4*)&As[k][ty * 4];
      const float4 a1 = *(const float4*)&As[k][64 + ty * 4];
      const float4 b  = *(const float4*)&Bs[k][tx * 4];
      const float ar[8] = {a0.x, a0.y, a0.z, a0.w, a1.x, a1.y, a1.z, a1.w};
      const float br[4] = {b.x, b.y, b.z, b.w};
#pragma unroll
      for (int r = 0; r < 8; ++r)
#pragma unroll
        for (int c = 0; c < 4; ++c)
          acc[r][c] = fmaf(ar[r], br[c], acc[r][c]);
    }
  }

  const float4 bv = *(const float4*)&bb[colOff + tx * 4];
  const float br[4] = {bv.x, bv.y, bv.z, bv.w};
#pragma unroll
  for (int r = 0; r < 8; ++r) {
    const int row = rowBase + ((r < 4) ? (ty * 4 + r) : (64 + ty * 4 + r - 4));
    float4 o;
    o.x = acc[r][0] + br[0]; o.y = acc[r][1] + br[1];
    o.z = acc[r][2] + br[2]; o.w = acc[r][3] + br[3];
    const size_t off = (size_t)row * DIMK + colOff + tx * 4;
    *(float4*)&Out[off] = o;
    ushort4 ob;
    ob.x = f2bf(o.x); ob.y = f2bf(o.y); ob.z = f2bf(o.z); ob.w = f2bf(o.w);
    *(ushort4*)&Outb[off] = ob;
  }
}

// ---------------------------------------------------------------------------
// Screen: bf16 MFMA GEMM + epilogue. NEW: Cs holds bf16 (18 KB, not 35 KB
// fp32) -> total LDS 34.8 KB -> 4 blocks/CU (was 3). The packed uint4 read
// back from Cs IS the Sc payload (stored as-is, same write pattern as the
// measured-194MB round-5/7 version). tmax = max over STORED bf16 values
// (consistent with what collect compares; t shifts down only -> superset).
// ---------------------------------------------------------------------------
__global__ __launch_bounds__(256, 4)
void screen_store(const unsigned short* __restrict__ Ehb,
                  const unsigned short* __restrict__ Etb,
                  float* __restrict__ tmax, unsigned short* __restrict__ Sc) {
  __shared__ unsigned short As[BM * BK];   // 8 KB
  __shared__ unsigned short Bs[BN * BK];   // 8 KB
  __shared__ unsigned short Csb[BM * 72];  // 18 KB, stride 72 (16B-aligned rows)

  const int tid = threadIdx.x;
  const int rowBase = blockIdx.x * BM;
  const int strip = blockIdx.y;
  const int w = tid >> 6, lane = tid & 63;
  const int q = lane >> 4, l15 = lane & 15;
  const int wr = (w & 1) * 64, wc = (w >> 1) * 64;
  const int rr = tid >> 1, hq = tid & 1;   // epilogue: row / 32-col chunk

  const int c0 = tid, c1 = tid + 256;
  const int wb0 = __builtin_amdgcn_readfirstlane(tid & ~63);
  const int wb1 = wb0 + 256;
  const int ar0 = c0 >> 2, ac0 = (c0 & 3) * 8;
  const int ar1 = c1 >> 2, ac1 = (c1 & 3) * 8;

  for (int ct = 0; ct < SCOLS2; ct += BN) {
    const int colBase = strip * SCOLS2 + ct;
    const int tileG = colBase >> 7;          // global 128-col tile index
    f32x4 acc[4][4];
#pragma unroll
    for (int i = 0; i < 4; ++i)
#pragma unroll
      for (int j = 0; j < 4; ++j) acc[i][j] = (f32x4){0.f, 0.f, 0.f, 0.f};

    for (int kt = 0; kt < DIMK; kt += BK) {
      __syncthreads();
      gld16(Ehb + (size_t)(rowBase + ar0) * DIMK + kt + ac0, As + wb0 * 8);
      gld16(Ehb + (size_t)(rowBase + ar1) * DIMK + kt + ac1, As + wb1 * 8);
      gld16(Etb + (size_t)(colBase + ar0) * DIMK + kt + ac0, Bs + wb0 * 8);
      gld16(Etb + (size_t)(colBase + ar1) * DIMK + kt + ac1, Bs + wb1 * 8);
      __syncthreads();   // drains vmcnt (global_load_lds) + orders LDS

      bf16x8 af[4], bf[4];
#pragma unroll
      for (int i = 0; i < 4; ++i)
        af[i] = *(const bf16x8*)&As[(wr + i * 16 + l15) * BK + q * 8];
#pragma unroll
      for (int j = 0; j < 4; ++j)
        bf[j] = *(const bf16x8*)&Bs[(wc + j * 16 + l15) * BK + q * 8];
#pragma unroll
      for (int i = 0; i < 4; ++i)
#pragma unroll
        for (int j = 0; j < 4; ++j)
          acc[i][j] = __builtin_amdgcn_mfma_f32_16x16x32_bf16(af[i], bf[j], acc[i][j], 0, 0, 0);
    }

    // Epilogue per 64-col half: bf16 dump -> (chunk max from stored, Sc store).
#pragma unroll
    for (int half = 0; half < 2; ++half) {
      if ((w >> 1) == half) {
#pragma unroll
        for (int i = 0; i < 4; ++i)
#pragma unroll
          for (int j = 0; j < 4; ++j)
#pragma unroll
            for (int rg = 0; rg < 4; ++rg)
              Csb[(wr + i * 16 + q * 4 + rg) * 72 + j * 16 + l15] = f2bf(acc[i][j][rg]);
      }
      __syncthreads();
      float m = -INFINITY;
      uint4 buf[4];
#pragma unroll
      for (int k = 0; k < 4; ++k) {
        buf[k] = *(const uint4*)&Csb[rr * 72 + hq * 32 + k * 8];
        const unsigned int uu[4] = {buf[k].x, buf[k].y, buf[k].z, buf[k].w};
#pragma unroll
        for (int e = 0; e < 4; ++e) {
          m = fmaxf(m, __uint_as_float(uu[e] << 16));
          m = fmaxf(m, __uint_as_float(uu[e] & 0xFFFF0000u));
        }
      }
      tmax[(size_t)(rowBase + rr) * NQ + tileG * 4 + half * 2 + hq] = m;
      uint4* dst = (uint4*)&Sc[(size_t)(rowBase + rr) * NROWS + colBase + half * 64 + hq * 32];
#pragma unroll
      for (int k = 0; k < 4; ++k) dst[k] = buf[k];
      __syncthreads();   // readback done before next dump overwrites Csb
    }
  }
}

// ---------------------------------------------------------------------------
// Collect (+ inlined per-row threshold): wave per row. Phase 1: t = (10th-
// best of the row's 256 group maxes) - TMARGIN via 10-round wave-max
// knockout (value-exact selection; duplicates can only lower t -> superset).
// Phase 2: scan stored bf16 logits vs t, append candidates (LDS counter).
// ---------------------------------------------------------------------------
__global__ __launch_bounds__(256)
void collect_scan(const unsigned short* __restrict__ Sc,
                  const float* __restrict__ tmax,
                  int* __restrict__ cnt, int* __restrict__ cand) {
  __shared__ int lcnt[4];
  const int lane = threadIdx.x & 63;
  const int wid = threadIdx.x >> 6;
  const int r = blockIdx.x * 4 + wid;

  if (threadIdx.x < 4) lcnt[threadIdx.x] = 0;
  __syncthreads();

  // --- threshold: 10 rounds of wave-max knockout over 256 group maxes ---
  const f32x4 gm = *(const f32x4*)&tmax[(size_t)r * NQ + lane * 4];
  float a0 = gm[0], a1 = gm[1], a2 = gm[2], a3 = gm[3];
  float g = -INFINITY;
#pragma unroll 1
  for (int j = 0; j < TOPK; ++j) {
    const float lm = fmaxf(fmaxf(a0, a1), fmaxf(a2, a3));
    g = lm;
#pragma unroll
    for (int off = 32; off > 0; off >>= 1) g = fmaxf(g, __shfl_xor(g, off, 64));
    const unsigned long long ball = __ballot(lm == g);
    const int src = __ffsll((long long)ball) - 1;
    if (lane == src) {
      if      (a0 == g) a0 = -INFINITY;
      else if (a1 == g) a1 = -INFINITY;
      else if (a2 == g) a2 = -INFINITY;
      else              a3 = -INFINITY;
    }
  }
  const float tt = g - TMARGIN;

  // --- scan the stored bf16 logit row ---
  const unsigned short* row = Sc + (size_t)r * NROWS;
#pragma unroll 1
  for (int it = 0; it < NROWS / 512; ++it) {
    const int c0 = it * 512 + lane * 8;
    const uint4 u = *(const uint4*)&row[c0];
    const unsigned int uu[4] = {u.x, u.y, u.z, u.w};
#pragma unroll
    for (int e = 0; e < 4; ++e) {
      const float lo = __uint_as_float(uu[e] << 16);
      const float hi = __uint_as_float(uu[e] & 0xFFFF0000u);
      if (lo >= tt) {
        const int p = atomicAdd(&lcnt[wid], 1);
        if (p < CAP) cand[(size_t)r * CAP + p] = c0 + 2 * e;
      }
      if (hi >= tt) {
        const int p = atomicAdd(&lcnt[wid], 1);
        if (p < CAP) cand[(size_t)r * CAP + p] = c0 + 2 * e + 1;
      }
    }
  }
  __syncthreads();
  if (threadIdx.x < 4) cnt[blockIdx.x * 4 + threadIdx.x] = min(lcnt[threadIdx.x], CAP);
}

// ---------------------------------------------------------------------------
// Rescore + finalize fused: wave per row; lane per candidate slot. Chain is
// BIT-IDENTICAL to rounds 3-7 (sequential fmaf k=0..511, then *SCALE).
// Top-10 via deterministic wave-max (tie: min col); softmax summed in the
// same sequential order as the old finalize. Output: [src][dst][weight].
// ---------------------------------------------------------------------------
__global__ __launch_bounds__(256)
void rescore_topk(const float* __restrict__ Eh, const float* __restrict__ Et,
                  const int* __restrict__ cnt, const int* __restrict__ cand,
                  float* __restrict__ out) {
  const int lane = threadIdx.x & 63;
  const int r = blockIdx.x * 4 + (threadIdx.x >> 6);
  const int n = cnt[r];
  const bool active = lane < n;
  const int col = active ? cand[(size_t)r * CAP + lane] : 0;

  const float* a = Eh + (size_t)r * DIMK;
  const float* b = Et + (size_t)col * DIMK;
  float p = 0.f;
#pragma unroll 4
  for (int k = 0; k < DIMK; k += 4) {
    const float4 av = *(const float4*)&a[k];
    const float4 bv = *(const float4*)&b[k];
    p = fmaf(av.x, bv.x, p);
    p = fmaf(av.y, bv.y, p);
    p = fmaf(av.z, bv.z, p);
    p = fmaf(av.w, bv.w, p);
  }
  float v = active ? p * SCALE : -INFINITY;
  const int vc = active ? col : 0x7FFFFFFF;

  // 10 rounds of wave-max (tie -> min col); lane j keeps round-j winner.
  float myv = -INFINITY; int myc = 0; float m = 0.f;
  float vv = v; int cc2 = vc;
#pragma unroll 1
  for (int j = 0; j < TOPK; ++j) {
    float bvv = vv; int bcc = cc2;
#pragma unroll
    for (int off = 32; off > 0; off >>= 1) {
      const float ov = __shfl_xor(bvv, off, 64);
      const int oc = __shfl_xor(bcc, off, 64);
      if (ov > bvv || (ov == bvv && oc < bcc)) { bvv = ov; bcc = oc; }
    }
    if (j == 0) m = bvv;
    if (lane == j) { myv = bvv; myc = bcc; }
    if (vv == bvv && cc2 == bcc) vv = -INFINITY;   // knock out (cols unique)
  }

  // softmax: gather the 10 values, sum sequentially (same order as before).
  float sum = 0.f;
#pragma unroll
  for (int j = 0; j < TOPK; ++j) sum += expf(__shfl(myv, j, 64) - m);
  const float inv = 1.0f / sum;

  if (lane < TOPK) {
    const size_t ro = (size_t)r * TOPK + lane;
    out[ro] = (float)r;                                   // src
    out[(size_t)NROWS * TOPK + ro] = (float)myc;          // dst
    out[2 * (size_t)NROWS * TOPK + ro] = expf(myv - m) * inv;  // weight
  }
}

// ---------------------------------------------------------------------------
extern "C" void kernel_launch(void* const* d_in, const int* in_sizes, int n_in,
                              void* d_out, int out_size, void* d_ws, size_t ws_size,
                              hipStream_t stream) {
  const float* X  = (const float*)d_in[0];
  const float* Wh = (const float*)d_in[1];
  const float* bh = (const float*)d_in[2];
  const float* Wt = (const float*)d_in[3];
  const float* bt = (const float*)d_in[4];
  float* out = (float*)d_out;

  char* ws = (char*)d_ws;
  const size_t embB  = (size_t)NROWS * DIMK * sizeof(float);          // 16 MB
  const size_t embBH = (size_t)NROWS * DIMK * sizeof(unsigned short); //  8 MB
  const size_t tmaxB = (size_t)NROWS * NQ * sizeof(float);            //  8 MB
  const size_t cntB  = (size_t)NROWS * sizeof(int);                   // 32 KB
  const size_t candB = (size_t)NROWS * CAP * sizeof(int);             //  2 MB
  float* Eh   = (float*)ws;
  float* Et   = (float*)(ws + embB);
  unsigned short* Ehb = (unsigned short*)(ws + 2 * embB);
  unsigned short* Etb = (unsigned short*)(ws + 2 * embB + embBH);
  float* tmax = (float*)(ws + 2 * embB + 2 * embBH);
  int*   cnt  = (int*)(ws + 2 * embB + 2 * embBH + tmaxB);
  int*   cand = (int*)(ws + 2 * embB + 2 * embBH + tmaxB + cntB);
  unsigned short* Sc = (unsigned short*)
      (ws + 2 * embB + 2 * embBH + tmaxB + cntB + candB);
  // total ws use ~186 MB (fits: rounds 5-7 used ~190 MB)

  dim3 blk(NTHREADS);
  dim3 g1(NROWS / ETM, (2 * DIMK) / ETN);      // 64 x 16
  embed_gemm<<<g1, blk, 0, stream>>>(X, Wh, bh, Wt, bt, Eh, Et, Ehb, Etb);

  dim3 g2(NROWS / BM, NS2);                    // 64 x 16 (strip structure)
  screen_store<<<g2, blk, 0, stream>>>(Ehb, Etb, tmax, Sc);

  collect_scan<<<NROWS / 4, blk, 0, stream>>>(Sc, tmax, cnt, cand);

  rescore_topk<<<NROWS / 4, blk, 0, stream>>>(Eh, Et, cnt, cand, out);
}